// Round 3
// baseline (218.811 us; speedup 1.0000x reference)
//
#include <hip/hip_runtime.h>
#include <math.h>

#define NBINS 1000
#define NDIM 64
#define DIMS_PER_BLOCK 8
#define DIM_GROUPS (NDIM / DIMS_PER_BLOCK)      // 8
#define BLOCK_THREADS 1024
#define ROWS_PER_ITER (BLOCK_THREADS / 2)       // 512 rows per block half-step
#define ROW_BLOCKS 128                           // %8==0 -> all dim-groups of a row
                                                 // chunk on the same XCD (id=x+128y,
                                                 // XCD=id%8=x%8) -> 32B/row partial
                                                 // lines merge in that XCD's L2.

// zero the log_det region (atomic fallback path only)
__global__ __launch_bounds__(1024) void mg_zero(float* __restrict__ p, int n) {
    int i = blockIdx.x * blockDim.x + threadIdx.x;
    if (i < n) p[i] = 0.0f;
}

// final reduce: log_det[row] = sum over 8 dim-group partials in ws
__global__ __launch_bounds__(256) void mg_reduce(const float* __restrict__ ws,
                                                 float* __restrict__ out, int B) {
    int row = blockIdx.x * blockDim.x + threadIdx.x;
    if (row >= B) return;
    float s = 0.0f;
#pragma unroll
    for (int g = 0; g < DIM_GROUPS; ++g) s += ws[(size_t)g * B + row];
    out[row] = s;
}

// per-dim math: exact-fixup + interp + Giles erfinv. MACRO so knots[] stays a
// direct LDS access (no generic-pointer fallout). Updates php/ss, writes zout.
#define DIM_MATH(xd_, base_, i_, a_, b_, sc_, php_, ss_, zout_)                   \
    {                                                                             \
        float xd = (xd_);                                                         \
        int i = (i_);                                                             \
        float2 a = (a_), b = (b_);                                                \
        if (__builtin_expect((xd > b.x && i < NBINS - 2) ||                       \
                             (xd <= a.x && i > 0), 0)) {                          \
            while (xd > b.x && i < NBINS - 2) {                                   \
                ++i; a = b; b = knots[(base_) + i + 1];                           \
            }                                                                     \
            while (xd <= a.x && i > 0) {                                          \
                --i; b = a; a = knots[(base_) + i];                               \
            }                                                                     \
        }                                                                         \
        float slope = (b.y - a.y) * (sc_);                                        \
        float u = fmaf(slope, xd - a.x, a.y);                                     \
        float ph = fmaxf(slope, 1e-12f);                                          \
        u = fminf(fmaxf(u, 1e-6f), 1.0f - 1e-6f);                                 \
        float e1 = fminf(fmaxf(fmaf(2.0f, u, -1.0f), -0.99999f), 0.99999f);       \
        float wv = -0.6931471805599453f *                                         \
                   __builtin_amdgcn_logf(fmaf(-e1, e1, 1.0f));                    \
        float t = wv - 2.5f;                                                      \
        float p = 2.81022636e-08f;                                                \
        p = fmaf(p, t, 3.43273939e-07f);                                          \
        p = fmaf(p, t, -3.5233877e-06f);                                          \
        p = fmaf(p, t, -4.39150654e-06f);                                         \
        p = fmaf(p, t, 0.00021858087f);                                           \
        p = fmaf(p, t, -0.00125372503f);                                          \
        p = fmaf(p, t, -0.00417768164f);                                          \
        p = fmaf(p, t, 0.246640727f);                                             \
        p = fmaf(p, t, 1.50140941f);                                              \
        if (wv >= 5.0f) {                                                         \
            float tq = sqrtf(wv) - 3.0f;                                          \
            float pt = -0.000200214257f;                                          \
            pt = fmaf(pt, tq, 0.000100950558f);                                   \
            pt = fmaf(pt, tq, 0.00134934322f);                                    \
            pt = fmaf(pt, tq, -0.00367342844f);                                   \
            pt = fmaf(pt, tq, 0.00573950773f);                                    \
            pt = fmaf(pt, tq, -0.0076224613f);                                    \
            pt = fmaf(pt, tq, 0.00943887047f);                                    \
            pt = fmaf(pt, tq, 1.00167406f);                                       \
            pt = fmaf(pt, tq, 2.83297682f);                                       \
            p = pt;                                                               \
        }                                                                         \
        float z = 1.4142135623730951f * p * e1; /* |z|<=4.418, ref clamp dead */  \
        (zout_) = z;                                                              \
        (ss_) = fmaf(z, z, (ss_));                                                \
        (php_) *= ph;                                                             \
    }

// Block owns 8 dims; knots (x_i,c_i) staged in LDS (64 KB).
// Thread handles 4 dims of TWO rows (r, r+rstride) per iteration: two
// independent gather+math chains -> lgkm latency of one hides under the
// other's fma stream (R2 showed 57% VALU-idle, latency-bound, occupancy
// is thread-capped at 2048/CU so ILP is the only lever).
// Lanes 2i/2i+1 -> adjacent 16B chunks = 32B/row coalesced; next pair
// prefetched before the math; partner-lane shfl reduce; ws partials.
template <bool USE_WS>
__global__ __launch_bounds__(BLOCK_THREADS, 8)
void mg_main(const float* __restrict__ x,
             const float* __restrict__ xvals,
             const float* __restrict__ cdf,
             float* __restrict__ out, float* __restrict__ ws, int B) {
    __shared__ float2 knots[DIMS_PER_BLOCK * NBINS];   // 64000 B

    const int dimbase = blockIdx.y * DIMS_PER_BLOCK;

    {   // vectorized stage: 2000 float4s from each table
        const float4* xv4 = (const float4*)(xvals + (size_t)dimbase * NBINS);
        const float4* cd4 = (const float4*)(cdf + (size_t)dimbase * NBINS);
        for (int k = threadIdx.x; k < DIMS_PER_BLOCK * NBINS / 4; k += BLOCK_THREADS) {
            float4 a = xv4[k], c = cd4[k];
            knots[k * 4 + 0] = make_float2(a.x, c.x);
            knots[k * 4 + 1] = make_float2(a.y, c.y);
            knots[k * 4 + 2] = make_float2(a.z, c.z);
            knots[k * 4 + 3] = make_float2(a.w, c.w);
        }
    }
    __syncthreads();

    const int dl = (threadIdx.x & 1) * 4;                // local dims dl..dl+3
    const int qidx = blockIdx.y * 2 + (threadIdx.x & 1); // float4 index within row

    float scale[4], bias[4];
#pragma unroll
    for (int j = 0; j < 4; ++j) {
        float l = knots[(dl + j) * NBINS].x;
        float h = knots[(dl + j) * NBINS + NBINS - 1].x;
        float s = (float)(NBINS - 1) / (h - l);          // == 1/step_d
        scale[j] = s;
        bias[j] = -l * s;
    }

    const int rstride = gridDim.x * ROWS_PER_ITER;       // pair separation
    const int ostride = 2 * rstride;                     // outer loop step
    int r0 = blockIdx.x * ROWS_PER_ITER + (threadIdx.x >> 1);

    float4 xq0 = make_float4(0.f, 0.f, 0.f, 0.f);
    float4 xq1 = make_float4(0.f, 0.f, 0.f, 0.f);
    if (r0 < B) xq0 = ((const float4*)x)[(size_t)r0 * (NDIM / 4) + qidx];
    if (r0 + rstride < B)
        xq1 = ((const float4*)x)[(size_t)(r0 + rstride) * (NDIM / 4) + qidx];

    for (; r0 < B; r0 += ostride) {
        const int r1 = r0 + rstride;
        const int p0 = r0 + ostride, p1 = r1 + ostride;
        float4 xn0 = make_float4(0.f, 0.f, 0.f, 0.f);
        float4 xn1 = make_float4(0.f, 0.f, 0.f, 0.f);
        if (p0 < B) xn0 = ((const float4*)x)[(size_t)p0 * (NDIM / 4) + qidx];
        if (p1 < B) xn1 = ((const float4*)x)[(size_t)p1 * (NDIM / 4) + qidx];

        float xv0[4] = {xq0.x, xq0.y, xq0.z, xq0.w};
        float xv1[4] = {xq1.x, xq1.y, xq1.z, xq1.w};

        int i0[4], i1[4];
#pragma unroll
        for (int j = 0; j < 4; ++j) {
            int i = (int)fmaf(xv0[j], scale[j], bias[j]);
            i0[j] = min(max(i, 0), NBINS - 2);
            i = (int)fmaf(xv1[j], scale[j], bias[j]);
            i1[j] = min(max(i, 0), NBINS - 2);
        }

        // issue ALL 16 gathers before either math block: both chains in flight
        float2 kl0[4], kr0[4], kl1[4], kr1[4];
#pragma unroll
        for (int j = 0; j < 4; ++j) {
            kl0[j] = knots[(dl + j) * NBINS + i0[j]];
            kr0[j] = knots[(dl + j) * NBINS + i0[j] + 1];
        }
#pragma unroll
        for (int j = 0; j < 4; ++j) {
            kl1[j] = knots[(dl + j) * NBINS + i1[j]];
            kr1[j] = knots[(dl + j) * NBINS + i1[j] + 1];
        }

        float z0[4], z1[4];
        float php0 = 1.0f, ss0 = 0.0f, php1 = 1.0f, ss1 = 0.0f;
#pragma unroll
        for (int j = 0; j < 4; ++j)
            DIM_MATH(xv0[j], (dl + j) * NBINS, i0[j], kl0[j], kr0[j], scale[j],
                     php0, ss0, z0[j]);
#pragma unroll
        for (int j = 0; j < 4; ++j)
            DIM_MATH(xv1[j], (dl + j) * NBINS, i1[j], kl1[j], kr1[j], scale[j],
                     php1, ss1, z1[j]);

        ((float4*)out)[(size_t)r0 * (NDIM / 4) + qidx] =
            make_float4(z0[0], z0[1], z0[2], z0[3]);
        if (r1 < B)
            ((float4*)out)[(size_t)r1 * (NDIM / 4) + qidx] =
                make_float4(z1[0], z1[1], z1[2], z1[3]);

        // term = sum_j [log(p_hat_j) + 0.5 z^2 + log(sqrt(2pi))]
        // -log(phi+1e-12) == 0.5 z^2 + 0.9189385 to 4.3e-8 abs since |z|<=4.418
        float term0 = fmaf(0.5f, ss0, 4.0f * 0.9189385332046727f) +
                      0.6931471805599453f * __builtin_amdgcn_logf(php0);
        float term1 = fmaf(0.5f, ss1, 4.0f * 0.9189385332046727f) +
                      0.6931471805599453f * __builtin_amdgcn_logf(php1);

        term0 += __shfl_xor(term0, 1, 64);   // partner covers the other 4 dims
        term1 += __shfl_xor(term1, 1, 64);
        if ((threadIdx.x & 1) == 0) {
            if constexpr (USE_WS) {
                ws[(size_t)blockIdx.y * B + r0] = term0;
                if (r1 < B) ws[(size_t)blockIdx.y * B + r1] = term1;
            } else {
                atomicAdd(out + (size_t)B * NDIM + r0, term0);
                if (r1 < B) atomicAdd(out + (size_t)B * NDIM + r1, term1);
            }
        }

        xq0 = xn0;
        xq1 = xn1;
    }
}

extern "C" void kernel_launch(void* const* d_in, const int* in_sizes, int n_in,
                              void* d_out, int out_size, void* d_ws, size_t ws_size,
                              hipStream_t stream) {
    const float* x = (const float*)d_in[0];
    const float* xvals = (const float*)d_in[1];
    const float* cdf = (const float*)d_in[2];
    float* out = (float*)d_out;
    int B = in_sizes[0] / NDIM;

    const size_t ws_need = (size_t)DIM_GROUPS * B * sizeof(float);
    dim3 grid(ROW_BLOCKS, DIM_GROUPS);

    if (ws_size >= ws_need) {
        float* ws = (float*)d_ws;
        hipLaunchKernelGGL((mg_main<true>), grid, dim3(BLOCK_THREADS), 0, stream,
                           x, xvals, cdf, out, ws, B);
        hipLaunchKernelGGL(mg_reduce, dim3((B + 255) / 256), dim3(256), 0, stream,
                           ws, out + (size_t)B * NDIM, B);
    } else {
        hipLaunchKernelGGL(mg_zero, dim3((B + 1023) / 1024), dim3(1024), 0, stream,
                           out + (size_t)B * NDIM, B);
        hipLaunchKernelGGL((mg_main<false>), grid, dim3(BLOCK_THREADS), 0, stream,
                           x, xvals, cdf, out, (float*)nullptr, B);
    }
}

// Round 4
// 144.142 us; speedup vs baseline: 1.5180x; 1.5180x over previous
//
#include <hip/hip_runtime.h>
#include <math.h>

#define NBINS 1000
#define NDIM 64
#define DIMS_PER_BLOCK 8
#define DIM_GROUPS (NDIM / DIMS_PER_BLOCK)      // 8
#define BLOCK_THREADS 1024
#define ROWS_PER_ITER (BLOCK_THREADS / 2)       // 512 rows per block-iteration
#define ROW_BLOCKS 128                           // %8==0 -> all dim-groups of a row
                                                 // chunk on the same XCD (id=x+128y,
                                                 // XCD=id%8=x%8) -> 32B/row partial
                                                 // lines merge in that XCD's L2.
                                                 // DO NOT interleave distant rows:
                                                 // R3 (stride-65536 pair) thrashed
                                                 // the merge window, FETCH 66->178MB.

// zero the log_det region (atomic fallback path only)
__global__ __launch_bounds__(1024) void mg_zero(float* __restrict__ p, int n) {
    int i = blockIdx.x * blockDim.x + threadIdx.x;
    if (i < n) p[i] = 0.0f;
}

// final reduce: log_det[row] = sum over 8 dim-group partials in ws
__global__ __launch_bounds__(256) void mg_reduce(const float* __restrict__ ws,
                                                 float* __restrict__ out, int B) {
    int row = blockIdx.x * blockDim.x + threadIdx.x;
    if (row >= B) return;
    float s = 0.0f;
#pragma unroll
    for (int g = 0; g < DIM_GROUPS; ++g) s += ws[(size_t)g * B + row];
    out[row] = s;
}

// per-dim math: exact-fixup + interp + Giles erfinv. MACRO so knots[] stays a
// direct LDS access (no generic-pointer fallout). Updates php/ss, writes zout.
#define DIM_MATH(xd_, base_, i_, a_, b_, sc_, php_, ss_, zout_)                   \
    {                                                                             \
        float xd = (xd_);                                                         \
        int i = (i_);                                                             \
        float2 a = (a_), b = (b_);                                                \
        if (__builtin_expect((xd > b.x && i < NBINS - 2) ||                       \
                             (xd <= a.x && i > 0), 0)) {                          \
            while (xd > b.x && i < NBINS - 2) {                                   \
                ++i; a = b; b = knots[(base_) + i + 1];                           \
            }                                                                     \
            while (xd <= a.x && i > 0) {                                          \
                --i; b = a; a = knots[(base_) + i];                               \
            }                                                                     \
        }                                                                         \
        float slope = (b.y - a.y) * (sc_);                                        \
        float u = fmaf(slope, xd - a.x, a.y);                                     \
        float ph = fmaxf(slope, 1e-12f);                                          \
        u = fminf(fmaxf(u, 1e-6f), 1.0f - 1e-6f);                                 \
        float e1 = fminf(fmaxf(fmaf(2.0f, u, -1.0f), -0.99999f), 0.99999f);       \
        float wv = -0.6931471805599453f *                                         \
                   __builtin_amdgcn_logf(fmaf(-e1, e1, 1.0f));                    \
        float t = wv - 2.5f;                                                      \
        float p = 2.81022636e-08f;                                                \
        p = fmaf(p, t, 3.43273939e-07f);                                          \
        p = fmaf(p, t, -3.5233877e-06f);                                          \
        p = fmaf(p, t, -4.39150654e-06f);                                         \
        p = fmaf(p, t, 0.00021858087f);                                           \
        p = fmaf(p, t, -0.00125372503f);                                          \
        p = fmaf(p, t, -0.00417768164f);                                          \
        p = fmaf(p, t, 0.246640727f);                                             \
        p = fmaf(p, t, 1.50140941f);                                              \
        if (wv >= 5.0f) {                                                         \
            float tq = sqrtf(wv) - 3.0f;                                          \
            float pt = -0.000200214257f;                                          \
            pt = fmaf(pt, tq, 0.000100950558f);                                   \
            pt = fmaf(pt, tq, 0.00134934322f);                                    \
            pt = fmaf(pt, tq, -0.00367342844f);                                   \
            pt = fmaf(pt, tq, 0.00573950773f);                                    \
            pt = fmaf(pt, tq, -0.0076224613f);                                    \
            pt = fmaf(pt, tq, 0.00943887047f);                                    \
            pt = fmaf(pt, tq, 1.00167406f);                                       \
            pt = fmaf(pt, tq, 2.83297682f);                                       \
            p = pt;                                                               \
        }                                                                         \
        float z = 1.4142135623730951f * p * e1; /* |z|<=4.418, ref clamp dead */  \
        (zout_) = z;                                                              \
        (ss_) = fmaf(z, z, (ss_));                                                \
        (php_) *= ph;                                                             \
    }

// Block owns 8 dims; knots (x_i,c_i) staged in LDS (64 KB).
// MEMORY STRUCTURE = R2 (measured best: FETCH 66MB, WRITE 88MB).
// NEW in R4: LDS-gather software pipeline. At the end of iteration k we
// compute the bin guesses from the already-prefetched xn and ISSUE the 8
// ds_read_b64 for iteration k+1; the math block then never waits on lgkm.
// (R2 counters: VALU port only 43% busy, HBM 35%, latency-bound.)
template <bool USE_WS>
__global__ __launch_bounds__(BLOCK_THREADS, 8)
void mg_main(const float* __restrict__ x,
             const float* __restrict__ xvals,
             const float* __restrict__ cdf,
             float* __restrict__ out, float* __restrict__ ws, int B) {
    __shared__ float2 knots[DIMS_PER_BLOCK * NBINS];   // 64000 B

    const int dimbase = blockIdx.y * DIMS_PER_BLOCK;

    {   // vectorized stage: 2000 float4s from each table
        const float4* xv4 = (const float4*)(xvals + (size_t)dimbase * NBINS);
        const float4* cd4 = (const float4*)(cdf + (size_t)dimbase * NBINS);
        for (int k = threadIdx.x; k < DIMS_PER_BLOCK * NBINS / 4; k += BLOCK_THREADS) {
            float4 a = xv4[k], c = cd4[k];
            knots[k * 4 + 0] = make_float2(a.x, c.x);
            knots[k * 4 + 1] = make_float2(a.y, c.y);
            knots[k * 4 + 2] = make_float2(a.z, c.z);
            knots[k * 4 + 3] = make_float2(a.w, c.w);
        }
    }
    __syncthreads();

    const int dl = (threadIdx.x & 1) * 4;                // local dims dl..dl+3
    const int qidx = blockIdx.y * 2 + (threadIdx.x & 1); // float4 index within row

    float scale[4], bias[4];
#pragma unroll
    for (int j = 0; j < 4; ++j) {
        float l = knots[(dl + j) * NBINS].x;
        float h = knots[(dl + j) * NBINS + NBINS - 1].x;
        float s = (float)(NBINS - 1) / (h - l);          // == 1/step_d
        scale[j] = s;
        bias[j] = -l * s;
    }

    const int rstride = gridDim.x * ROWS_PER_ITER;
    int row = blockIdx.x * ROWS_PER_ITER + (threadIdx.x >> 1);

    // iter-0 prologue: load x, guess bins, issue gathers
    float4 xq = make_float4(0.f, 0.f, 0.f, 0.f);
    if (row < B) xq = ((const float4*)x)[(size_t)row * (NDIM / 4) + qidx];

    int ii[4];
    float2 kl[4], kr[4];
    {
        float xv[4] = {xq.x, xq.y, xq.z, xq.w};
#pragma unroll
        for (int j = 0; j < 4; ++j) {
            int i = (int)fmaf(xv[j], scale[j], bias[j]);
            ii[j] = min(max(i, 0), NBINS - 2);
        }
#pragma unroll
        for (int j = 0; j < 4; ++j) {
            kl[j] = knots[(dl + j) * NBINS + ii[j]];
            kr[j] = knots[(dl + j) * NBINS + ii[j] + 1];
        }
    }

    for (; row < B; row += rstride) {
        const int nrow = row + rstride;
        float4 xn = make_float4(0.f, 0.f, 0.f, 0.f);
        if (nrow < B) xn = ((const float4*)x)[(size_t)nrow * (NDIM / 4) + qidx];

        // math on current row: gathers were issued LAST iteration, no lgkm wait
        float z4[4], php = 1.0f, sumsq = 0.0f;
        DIM_MATH(xq.x, (dl + 0) * NBINS, ii[0], kl[0], kr[0], scale[0],
                 php, sumsq, z4[0]);
        DIM_MATH(xq.y, (dl + 1) * NBINS, ii[1], kl[1], kr[1], scale[1],
                 php, sumsq, z4[1]);
        DIM_MATH(xq.z, (dl + 2) * NBINS, ii[2], kl[2], kr[2], scale[2],
                 php, sumsq, z4[2]);
        DIM_MATH(xq.w, (dl + 3) * NBINS, ii[3], kl[3], kr[3], scale[3],
                 php, sumsq, z4[3]);

        // issue NEXT iteration's gathers now (xn has arrived by end of math);
        // latency hides under stores + loop overhead + next-iter entry.
        {
            float xv[4] = {xn.x, xn.y, xn.z, xn.w};
#pragma unroll
            for (int j = 0; j < 4; ++j) {
                int i = (int)fmaf(xv[j], scale[j], bias[j]);
                ii[j] = min(max(i, 0), NBINS - 2);   // safe even for dummy xn=0
            }
#pragma unroll
            for (int j = 0; j < 4; ++j) {
                kl[j] = knots[(dl + j) * NBINS + ii[j]];
                kr[j] = knots[(dl + j) * NBINS + ii[j] + 1];
            }
        }

        ((float4*)out)[(size_t)row * (NDIM / 4) + qidx] =
            make_float4(z4[0], z4[1], z4[2], z4[3]);

        // term = sum_j [log(p_hat_j) + 0.5 z^2 + log(sqrt(2pi))]
        // -log(phi+1e-12) == 0.5 z^2 + 0.9189385 to 4.3e-8 abs since |z|<=4.418
        float term = fmaf(0.5f, sumsq, 4.0f * 0.9189385332046727f) +
                     0.6931471805599453f * __builtin_amdgcn_logf(php);

        term += __shfl_xor(term, 1, 64);   // partner lane covers the other 4 dims
        if ((threadIdx.x & 1) == 0) {
            if constexpr (USE_WS)
                ws[(size_t)blockIdx.y * B + row] = term;   // coalesced partial
            else
                atomicAdd(out + (size_t)B * NDIM + row, term);
        }

        xq = xn;
    }
}

extern "C" void kernel_launch(void* const* d_in, const int* in_sizes, int n_in,
                              void* d_out, int out_size, void* d_ws, size_t ws_size,
                              hipStream_t stream) {
    const float* x = (const float*)d_in[0];
    const float* xvals = (const float*)d_in[1];
    const float* cdf = (const float*)d_in[2];
    float* out = (float*)d_out;
    int B = in_sizes[0] / NDIM;

    const size_t ws_need = (size_t)DIM_GROUPS * B * sizeof(float);
    dim3 grid(ROW_BLOCKS, DIM_GROUPS);

    if (ws_size >= ws_need) {
        float* ws = (float*)d_ws;
        hipLaunchKernelGGL((mg_main<true>), grid, dim3(BLOCK_THREADS), 0, stream,
                           x, xvals, cdf, out, ws, B);
        hipLaunchKernelGGL(mg_reduce, dim3((B + 255) / 256), dim3(256), 0, stream,
                           ws, out + (size_t)B * NDIM, B);
    } else {
        hipLaunchKernelGGL(mg_zero, dim3((B + 1023) / 1024), dim3(1024), 0, stream,
                           out + (size_t)B * NDIM, B);
        hipLaunchKernelGGL((mg_main<false>), grid, dim3(BLOCK_THREADS), 0, stream,
                           x, xvals, cdf, out, (float*)nullptr, B);
    }
}